// Round 2
// baseline (4389.890 us; speedup 1.0000x reference)
//
#include <hip/hip_runtime.h>

constexpr int NB = 16;    // bases
constexpr int REFF = 9;   // relations

// W[r, fe] = sum_b comps[r,b] * bases[b, fe]
__global__ void compute_w_kernel(const float* __restrict__ comps,
                                 const float* __restrict__ bases,
                                 float* __restrict__ W, int FE, int total) {
  int idx = blockIdx.x * 256 + threadIdx.x;
  if (idx >= total) return;
  int r = idx / FE;
  int fe = idx - r * FE;
  float acc = 0.f;
#pragma unroll
  for (int b = 0; b < NB; ++b)
    acc += comps[r * NB + b] * bases[(size_t)b * FE + fe];
  W[idx] = acc;
}

// scatter pass for ONE relation: edges whose row is in [rbase, rbase+N)
// one wave per edge; 64 lanes x float4 = 256 floats
__global__ void spmm_rel_kernel(const float* __restrict__ vals,
                                const int* __restrict__ rows,
                                const int* __restrict__ cols,
                                const float* __restrict__ X,
                                float* __restrict__ agg,
                                int E, int rbase, int N) {
  int e = blockIdx.x * 4 + (threadIdx.x >> 6);
  if (e >= E) return;
  int row = rows[e] - rbase;
  if ((unsigned)row >= (unsigned)N) return;   // not this relation
  int lane = threadIdx.x & 63;
  float v = vals[e];
  float4 x = reinterpret_cast<const float4*>(X)[(size_t)cols[e] * 64 + lane];
  float* o = agg + (size_t)row * 256 + lane * 4;
  atomicAdd(o + 0, v * x.x);
  atomicAdd(o + 1, v * x.y);
  atomicAdd(o + 2, v * x.z);
  atomicAdd(o + 3, v * x.w);
}

// C[m, c] += sum_k A[m,k] * B[k,c];  A is M x 256, B is 256 x BNtot
template <int BN, int TNC>
__global__ void gemm_acc_kernel(const float* __restrict__ A,
                                const float* __restrict__ B,
                                float* __restrict__ C,
                                int M, int BNtot) {
  constexpr int BM = 64, BK = 32;
  __shared__ float As[BK][BM + 4];
  __shared__ float Bs[BK][BN];
  const int tid = threadIdx.x;
  const int tx = tid & 15, ty = tid >> 4;
  const int m0 = blockIdx.y * BM;
  const int c0 = blockIdx.x * BN;

  float acc[4][TNC];
#pragma unroll
  for (int i = 0; i < 4; ++i)
#pragma unroll
    for (int j = 0; j < TNC; ++j) acc[i][j] = 0.f;

  for (int kt = 0; kt < 256 / BK; ++kt) {
    const int k0 = kt * BK;
    // stage A (BM x BK) transposed into As[k][m]
#pragma unroll
    for (int l = 0; l < 2; ++l) {
      int idx = tid + l * 256;
      int i = idx >> 3;          // tile row 0..63
      int j = (idx & 7) << 2;    // k offset 0..28
      int m = m0 + i;
      float4 a = make_float4(0.f, 0.f, 0.f, 0.f);
      if (m < M)
        a = *reinterpret_cast<const float4*>(A + (size_t)m * 256 + k0 + j);
      As[j + 0][i] = a.x;
      As[j + 1][i] = a.y;
      As[j + 2][i] = a.z;
      As[j + 3][i] = a.w;
    }
    // stage B (BK x BN)
    constexpr int BQ = BK * BN / 4;  // float4 count: 512 (BN=64) or 256 (BN=32)
#pragma unroll
    for (int l = 0; l < BQ / 256; ++l) {
      int idx = tid + l * 256;
      int kk = idx / (BN / 4);
      int j = (idx % (BN / 4)) << 2;
      *reinterpret_cast<float4*>(&Bs[kk][j]) =
          *reinterpret_cast<const float4*>(B + (size_t)(k0 + kk) * BNtot + c0 + j);
    }
    __syncthreads();
#pragma unroll
    for (int kk = 0; kk < BK; ++kk) {
      float4 av = *reinterpret_cast<const float4*>(&As[kk][ty << 2]);
      float am[4] = {av.x, av.y, av.z, av.w};
      float bv[TNC];
#pragma unroll
      for (int j = 0; j < TNC; ++j) bv[j] = Bs[kk][tx * TNC + j];
#pragma unroll
      for (int i = 0; i < 4; ++i)
#pragma unroll
        for (int j = 0; j < TNC; ++j) acc[i][j] += am[i] * bv[j];
    }
    __syncthreads();
  }
  // epilogue: C += acc (blocks own disjoint tiles; launches are stream-ordered)
#pragma unroll
  for (int i = 0; i < 4; ++i) {
    int m = m0 + (ty << 2) + i;
    if (m >= M) continue;
    float* cp = C + (size_t)m * BNtot + c0 + tx * TNC;
    if constexpr (TNC == 4) {
      float4 old = *reinterpret_cast<float4*>(cp);
      *reinterpret_cast<float4*>(cp) =
          make_float4(old.x + acc[i][0], old.y + acc[i][1],
                      old.z + acc[i][2], old.w + acc[i][3]);
    } else {
      float2 old = *reinterpret_cast<float2*>(cp);
      *reinterpret_cast<float2*>(cp) =
          make_float2(old.x + acc[i][0], old.y + acc[i][1]);
    }
  }
}

// X[m, c] = act(X[m, c] + bias[c]);  Ctot power of two
__global__ void bias_act_kernel(float* __restrict__ X,
                                const float* __restrict__ bias,
                                int total, int cmask, int do_relu) {
  int idx = blockIdx.x * 256 + threadIdx.x;
  if (idx >= total) return;
  float v = X[idx] + bias[idx & cmask];
  if (do_relu) v = fmaxf(v, 0.f);
  X[idx] = v;
}

extern "C" void kernel_launch(void* const* d_in, const int* in_sizes, int n_in,
                              void* d_out, int out_size, void* d_ws, size_t ws_size,
                              hipStream_t stream) {
  const float* features = (const float*)d_in[0];
  const float* ver_vals = (const float*)d_in[1];
  const float* comps1   = (const float*)d_in[2];
  const float* bases1   = (const float*)d_in[3];
  const float* comps2   = (const float*)d_in[4];
  const float* bases2   = (const float*)d_in[5];
  const float* bias1    = (const float*)d_in[6];
  const float* bias2    = (const float*)d_in[7];
  const int* ver_rows   = (const int*)d_in[8];
  const int* ver_cols   = (const int*)d_in[9];

  const int N = in_sizes[0] / 256;   // 30000 entities
  const int E = in_sizes[1];         // 500000 edges

  // workspace layout (floats) — total 16,023,552 floats = 64.1 MB
  float* W1   = (float*)d_ws;                     // 9*256*256 = 589824
  float* W2   = W1 + (size_t)REFF * 256 * 256;    // 9*256*32  = 73728
  float* out1 = W2 + (size_t)REFF * 256 * 32;     // N*256
  float* agg  = out1 + (size_t)N * 256;           // N*256

  compute_w_kernel<<<(REFF * 65536) / 256, 256, 0, stream>>>(comps1, bases1, W1,
                                                             65536, REFF * 65536);
  compute_w_kernel<<<(REFF * 8192) / 256, 256, 0, stream>>>(comps2, bases2, W2,
                                                            8192, REFF * 8192);

  const int spmm_blocks = (E + 3) / 4;
  const dim3 g1(256 / 64, (N + 63) / 64);
  const dim3 g2(1, (N + 63) / 64);

  // ---- layer 1: out1 = relu(bias1 + sum_r agg_r @ W1[r]) ----
  hipMemsetAsync(out1, 0, (size_t)N * 256 * sizeof(float), stream);
  for (int r = 0; r < REFF; ++r) {
    hipMemsetAsync(agg, 0, (size_t)N * 256 * sizeof(float), stream);
    spmm_rel_kernel<<<spmm_blocks, 256, 0, stream>>>(ver_vals, ver_rows, ver_cols,
                                                     features, agg, E, r * N, N);
    gemm_acc_kernel<64, 4><<<g1, 256, 0, stream>>>(agg, W1 + (size_t)r * 65536,
                                                   out1, N, 256);
  }
  bias_act_kernel<<<(N * 256 + 255) / 256, 256, 0, stream>>>(out1, bias1,
                                                             N * 256, 255, 1);

  // ---- layer 2: out = bias2 + sum_r agg_r @ W2[r] ----
  float* out = (float*)d_out;
  hipMemsetAsync(out, 0, (size_t)N * 32 * sizeof(float), stream);
  for (int r = 0; r < REFF; ++r) {
    hipMemsetAsync(agg, 0, (size_t)N * 256 * sizeof(float), stream);
    spmm_rel_kernel<<<spmm_blocks, 256, 0, stream>>>(ver_vals, ver_rows, ver_cols,
                                                     out1, agg, E, r * N, N);
    gemm_acc_kernel<32, 2><<<g2, 256, 0, stream>>>(agg, W2 + (size_t)r * 8192,
                                                   out, N, 32);
  }
  bias_act_kernel<<<(N * 32 + 255) / 256, 256, 0, stream>>>(out, bias2,
                                                            N * 32, 31, 0);
}

// Round 3
// 1092.214 us; speedup vs baseline: 4.0193x; 4.0193x over previous
//
#include <hip/hip_runtime.h>

constexpr int NB = 16;    // bases
constexpr int REFF = 9;   // relations

__device__ __forceinline__ unsigned short f2bf(float f) {
  unsigned u = __float_as_uint(f);
  u += 0x7FFFu + ((u >> 16) & 1u);          // round-to-nearest-even
  return (unsigned short)(u >> 16);
}

// W[r, fe] = sum_b comps[r,b] * bases[b, fe]
__global__ void compute_w_kernel(const float* __restrict__ comps,
                                 const float* __restrict__ bases,
                                 float* __restrict__ W, int FE, int total) {
  int idx = blockIdx.x * 256 + threadIdx.x;
  if (idx >= total) return;
  int r = idx / FE;
  int fe = idx - r * FE;
  float acc = 0.f;
#pragma unroll
  for (int b = 0; b < NB; ++b)
    acc += comps[r * NB + b] * bases[(size_t)b * FE + fe];
  W[idx] = acc;
}

// ---------------- CSR build over NR = 9*N rows ----------------
__global__ void hist_kernel(const int* __restrict__ rows, int* __restrict__ deg,
                            int E) {
  int e = blockIdx.x * 256 + threadIdx.x;
  if (e < E) atomicAdd(&deg[rows[e]], 1);
}

// pass 1: per-block (1024 elems) sums
__global__ void scan1_kernel(const int* __restrict__ deg, int* __restrict__ bsum,
                             int NR) {
  __shared__ int s[256];
  int t = threadIdx.x;
  int base = blockIdx.x * 1024 + t * 4;
  int acc = 0;
#pragma unroll
  for (int q = 0; q < 4; ++q)
    if (base + q < NR) acc += deg[base + q];
  s[t] = acc;
  __syncthreads();
  for (int off = 128; off > 0; off >>= 1) {
    if (t < off) s[t] += s[t + off];
    __syncthreads();
  }
  if (t == 0) bsum[blockIdx.x] = s[0];
}

// pass 2: exclusive scan of bsum (NT <= 512), write grand total to ptr[NR]
__global__ void scan2_kernel(int* __restrict__ bsum, int* __restrict__ ptr,
                             int NT, int NR) {
  __shared__ int s[512];
  int t = threadIdx.x;
  int v = (t < NT) ? bsum[t] : 0;
  s[t] = v;
  __syncthreads();
  for (int off = 1; off < 512; off <<= 1) {
    int x = (t >= off) ? s[t - off] : 0;
    __syncthreads();
    s[t] += x;
    __syncthreads();
  }
  if (t < NT) bsum[t] = s[t] - v;          // exclusive
  if (t == NT - 1) ptr[NR] = s[t];         // total == E
}

// pass 3: ptr[i] = bsum_ex[block] + local exclusive scan of deg
__global__ void scan3_kernel(const int* __restrict__ deg,
                             const int* __restrict__ bsum,
                             int* __restrict__ ptr, int NR) {
  __shared__ int s[256];
  int t = threadIdx.x;
  int base = blockIdx.x * 1024 + t * 4;
  int d[4];
#pragma unroll
  for (int q = 0; q < 4; ++q)
    d[q] = (base + q < NR) ? deg[base + q] : 0;
  int tsum = d[0] + d[1] + d[2] + d[3];
  s[t] = tsum;
  __syncthreads();
  for (int off = 1; off < 256; off <<= 1) {
    int x = (t >= off) ? s[t - off] : 0;
    __syncthreads();
    s[t] += x;
    __syncthreads();
  }
  int off0 = bsum[blockIdx.x] + s[t] - tsum;
#pragma unroll
  for (int q = 0; q < 4; ++q) {
    if (base + q < NR) ptr[base + q] = off0;
    off0 += d[q];
  }
}

// fill: consume deg as cursor (counts down)
__global__ void fill_kernel(const int* __restrict__ rows, int* __restrict__ deg,
                            const int* __restrict__ ptr, int* __restrict__ eids,
                            int E) {
  int e = blockIdx.x * 256 + threadIdx.x;
  if (e >= E) return;
  int row = rows[e];
  int old = atomicSub(&deg[row], 1);
  eids[ptr[row] + old - 1] = e;
}

// ---------------- gather (SpMM without atomics) ----------------
// one wave per dst row; agg[row][256] in bf16
__global__ void gather_kernel(const float* __restrict__ vals,
                              const int* __restrict__ cols,
                              const int* __restrict__ eids,
                              const int* __restrict__ ptr,
                              const float* __restrict__ X,
                              unsigned short* __restrict__ agg,
                              int rbase, int N) {
  int row = blockIdx.x * 4 + (threadIdx.x >> 6);
  if (row >= N) return;
  int lane = threadIdx.x & 63;
  int g = rbase + row;
  int p0 = ptr[g], p1 = ptr[g + 1];
  float4 acc = make_float4(0.f, 0.f, 0.f, 0.f);
  for (int p = p0; p < p1; ++p) {
    int eid = eids[p];
    float v = vals[eid];
    int src = cols[eid];
    float4 x = reinterpret_cast<const float4*>(X)[(size_t)src * 64 + lane];
    acc.x += v * x.x;
    acc.y += v * x.y;
    acc.z += v * x.z;
    acc.w += v * x.w;
  }
  ushort4 o;
  o.x = f2bf(acc.x);
  o.y = f2bf(acc.y);
  o.z = f2bf(acc.z);
  o.w = f2bf(acc.w);
  reinterpret_cast<ushort4*>(agg)[(size_t)row * 64 + lane] = o;
}

// ---------------- GEMM: C[m,c] += sum_k A[m,k]*B[k,c], A bf16 M x 256 ----------------
template <int BN, int TNC>
__global__ void gemm_acc_kernel(const unsigned short* __restrict__ A,
                                const float* __restrict__ B,
                                float* __restrict__ C,
                                int M, int BNtot) {
  constexpr int BM = 64, BK = 32;
  __shared__ float As[BK][BM + 4];
  __shared__ float Bs[BK][BN];
  const int tid = threadIdx.x;
  const int tx = tid & 15, ty = tid >> 4;
  const int m0 = blockIdx.y * BM;
  const int c0 = blockIdx.x * BN;

  float acc[4][TNC];
#pragma unroll
  for (int i = 0; i < 4; ++i)
#pragma unroll
    for (int j = 0; j < TNC; ++j) acc[i][j] = 0.f;

  for (int kt = 0; kt < 256 / BK; ++kt) {
    const int k0 = kt * BK;
    // stage A (BM x BK) bf16 -> f32, transposed into As[k][m]
    {
      int i = tid >> 2;            // tile row 0..63
      int j = (tid & 3) << 3;      // k offset {0,8,16,24}
      int m = m0 + i;
      uint4 a = make_uint4(0u, 0u, 0u, 0u);
      if (m < M)
        a = *reinterpret_cast<const uint4*>(A + (size_t)m * 256 + k0 + j);
      As[j + 0][i] = __uint_as_float(a.x << 16);
      As[j + 1][i] = __uint_as_float(a.x & 0xFFFF0000u);
      As[j + 2][i] = __uint_as_float(a.y << 16);
      As[j + 3][i] = __uint_as_float(a.y & 0xFFFF0000u);
      As[j + 4][i] = __uint_as_float(a.z << 16);
      As[j + 5][i] = __uint_as_float(a.z & 0xFFFF0000u);
      As[j + 6][i] = __uint_as_float(a.w << 16);
      As[j + 7][i] = __uint_as_float(a.w & 0xFFFF0000u);
    }
    // stage B (BK x BN)
    constexpr int BQ = BK * BN / 4;
#pragma unroll
    for (int l = 0; l < BQ / 256; ++l) {
      int idx = tid + l * 256;
      int kk = idx / (BN / 4);
      int j = (idx % (BN / 4)) << 2;
      *reinterpret_cast<float4*>(&Bs[kk][j]) =
          *reinterpret_cast<const float4*>(B + (size_t)(k0 + kk) * BNtot + c0 + j);
    }
    __syncthreads();
#pragma unroll
    for (int kk = 0; kk < BK; ++kk) {
      float4 av = *reinterpret_cast<const float4*>(&As[kk][ty << 2]);
      float am[4] = {av.x, av.y, av.z, av.w};
      float bv[TNC];
#pragma unroll
      for (int j = 0; j < TNC; ++j) bv[j] = Bs[kk][tx * TNC + j];
#pragma unroll
      for (int i = 0; i < 4; ++i)
#pragma unroll
        for (int j = 0; j < TNC; ++j) acc[i][j] += am[i] * bv[j];
    }
    __syncthreads();
  }
#pragma unroll
  for (int i = 0; i < 4; ++i) {
    int m = m0 + (ty << 2) + i;
    if (m >= M) continue;
    float* cp = C + (size_t)m * BNtot + c0 + tx * TNC;
    if constexpr (TNC == 4) {
      float4 old = *reinterpret_cast<float4*>(cp);
      *reinterpret_cast<float4*>(cp) =
          make_float4(old.x + acc[i][0], old.y + acc[i][1],
                      old.z + acc[i][2], old.w + acc[i][3]);
    } else {
      float2 old = *reinterpret_cast<float2*>(cp);
      *reinterpret_cast<float2*>(cp) =
          make_float2(old.x + acc[i][0], old.y + acc[i][1]);
    }
  }
}

// X[m, c] = act(X[m, c] + bias[c])
__global__ void bias_act_kernel(float* __restrict__ X,
                                const float* __restrict__ bias,
                                int total, int cmask, int do_relu) {
  int idx = blockIdx.x * 256 + threadIdx.x;
  if (idx >= total) return;
  float v = X[idx] + bias[idx & cmask];
  if (do_relu) v = fmaxf(v, 0.f);
  X[idx] = v;
}

extern "C" void kernel_launch(void* const* d_in, const int* in_sizes, int n_in,
                              void* d_out, int out_size, void* d_ws, size_t ws_size,
                              hipStream_t stream) {
  const float* features = (const float*)d_in[0];
  const float* ver_vals = (const float*)d_in[1];
  const float* comps1   = (const float*)d_in[2];
  const float* bases1   = (const float*)d_in[3];
  const float* comps2   = (const float*)d_in[4];
  const float* bases2   = (const float*)d_in[5];
  const float* bias1    = (const float*)d_in[6];
  const float* bias2    = (const float*)d_in[7];
  const int* ver_rows   = (const int*)d_in[8];
  const int* ver_cols   = (const int*)d_in[9];

  const int N = in_sizes[0] / 256;   // 30000
  const int E = in_sizes[1];         // 500000
  const int NR = REFF * N;           // 270000
  const int NT = (NR + 1023) / 1024; // 264 scan blocks

  // ---- workspace layout (bytes; all regions 16B-aligned) ----
  char* p = (char*)d_ws;
  float* W1 = (float*)p;                 p += (size_t)REFF * 256 * 256 * 4;  // 2.36 MB
  float* W2 = (float*)p;                 p += (size_t)REFF * 256 * 32 * 4;   // 0.29 MB
  float* out1 = (float*)p;               p += (size_t)N * 256 * 4;           // 30.7 MB
  unsigned short* agg = (unsigned short*)p; p += (size_t)N * 256 * 2;        // 15.4 MB
  int* deg  = (int*)p;                   p += (size_t)NR * 4;                // 1.08 MB
  int* ptr  = (int*)p;                   p += (size_t)(NR + 4) * 4;          // 1.08 MB
  int* eids = (int*)p;                   p += (size_t)E * 4;                 // 2.0 MB
  int* bsum = (int*)p;                   p += 512 * 4;
  // total ~52.9 MB (< 64.09 MB proven-good)

  // ---- CSR build ----
  hipMemsetAsync(deg, 0, (size_t)NR * 4, stream);
  hist_kernel<<<(E + 255) / 256, 256, 0, stream>>>(ver_rows, deg, E);
  scan1_kernel<<<NT, 256, 0, stream>>>(deg, bsum, NR);
  scan2_kernel<<<1, 512, 0, stream>>>(bsum, ptr, NT, NR);
  scan3_kernel<<<NT, 256, 0, stream>>>(deg, bsum, ptr, NR);
  fill_kernel<<<(E + 255) / 256, 256, 0, stream>>>(ver_rows, deg, ptr, eids, E);

  // ---- weights ----
  compute_w_kernel<<<(REFF * 65536) / 256, 256, 0, stream>>>(comps1, bases1, W1,
                                                             65536, REFF * 65536);
  compute_w_kernel<<<(REFF * 8192) / 256, 256, 0, stream>>>(comps2, bases2, W2,
                                                            8192, REFF * 8192);

  const int gth_blocks = (N + 3) / 4;
  const dim3 g1(256 / 64, (N + 63) / 64);
  const dim3 g2(1, (N + 63) / 64);

  // ---- layer 1: out1 = relu(bias1 + sum_r (A_r @ X) @ W1_r) ----
  hipMemsetAsync(out1, 0, (size_t)N * 256 * 4, stream);
  for (int r = 0; r < REFF; ++r) {
    gather_kernel<<<gth_blocks, 256, 0, stream>>>(ver_vals, ver_cols, eids, ptr,
                                                  features, agg, r * N, N);
    gemm_acc_kernel<64, 4><<<g1, 256, 0, stream>>>(agg, W1 + (size_t)r * 65536,
                                                   out1, N, 256);
  }
  bias_act_kernel<<<(N * 256 + 255) / 256, 256, 0, stream>>>(out1, bias1,
                                                             N * 256, 255, 1);

  // ---- layer 2: out = bias2 + sum_r (A_r @ out1) @ W2_r ----
  float* out = (float*)d_out;
  hipMemsetAsync(out, 0, (size_t)N * 32 * 4, stream);
  for (int r = 0; r < REFF; ++r) {
    gather_kernel<<<gth_blocks, 256, 0, stream>>>(ver_vals, ver_cols, eids, ptr,
                                                  out1, agg, r * N, N);
    gemm_acc_kernel<32, 2><<<g2, 256, 0, stream>>>(agg, W2 + (size_t)r * 8192,
                                                   out, N, 32);
  }
  bias_act_kernel<<<(N * 32 + 255) / 256, 256, 0, stream>>>(out, bias2,
                                                            N * 32, 31, 0);
}

// Round 4
// 522.906 us; speedup vs baseline: 8.3952x; 2.0887x over previous
//
#include <hip/hip_runtime.h>

typedef __attribute__((ext_vector_type(8))) short bf16x8;
typedef __attribute__((ext_vector_type(4))) float f32x4;

constexpr int NB = 16;    // bases
constexpr int REFF = 9;   // relations

__device__ __forceinline__ unsigned short f2bf(float f) {
  unsigned u = __float_as_uint(f);
  u += 0x7FFFu + ((u >> 16) & 1u);          // round-to-nearest-even
  return (unsigned short)(u >> 16);
}

// ---------------- CSR build over NR = 9*N rows (proven in R3) ----------------
__global__ void hist_kernel(const int* __restrict__ rows, int* __restrict__ deg,
                            int E) {
  int e = blockIdx.x * 256 + threadIdx.x;
  if (e < E) atomicAdd(&deg[rows[e]], 1);
}

__global__ void scan1_kernel(const int* __restrict__ deg, int* __restrict__ bsum,
                             int NR) {
  __shared__ int s[256];
  int t = threadIdx.x;
  int base = blockIdx.x * 1024 + t * 4;
  int acc = 0;
#pragma unroll
  for (int q = 0; q < 4; ++q)
    if (base + q < NR) acc += deg[base + q];
  s[t] = acc;
  __syncthreads();
  for (int off = 128; off > 0; off >>= 1) {
    if (t < off) s[t] += s[t + off];
    __syncthreads();
  }
  if (t == 0) bsum[blockIdx.x] = s[0];
}

__global__ void scan2_kernel(int* __restrict__ bsum, int* __restrict__ ptr,
                             int NT, int NR) {
  __shared__ int s[512];
  int t = threadIdx.x;
  int v = (t < NT) ? bsum[t] : 0;
  s[t] = v;
  __syncthreads();
  for (int off = 1; off < 512; off <<= 1) {
    int x = (t >= off) ? s[t - off] : 0;
    __syncthreads();
    s[t] += x;
    __syncthreads();
  }
  if (t < NT) bsum[t] = s[t] - v;
  if (t == NT - 1) ptr[NR] = s[t];
}

__global__ void scan3_kernel(const int* __restrict__ deg,
                             const int* __restrict__ bsum,
                             int* __restrict__ ptr, int NR) {
  __shared__ int s[256];
  int t = threadIdx.x;
  int base = blockIdx.x * 1024 + t * 4;
  int d[4];
#pragma unroll
  for (int q = 0; q < 4; ++q)
    d[q] = (base + q < NR) ? deg[base + q] : 0;
  int tsum = d[0] + d[1] + d[2] + d[3];
  s[t] = tsum;
  __syncthreads();
  for (int off = 1; off < 256; off <<= 1) {
    int x = (t >= off) ? s[t - off] : 0;
    __syncthreads();
    s[t] += x;
    __syncthreads();
  }
  int off0 = bsum[blockIdx.x] + s[t] - tsum;
#pragma unroll
  for (int q = 0; q < 4; ++q) {
    if (base + q < NR) ptr[base + q] = off0;
    off0 += d[q];
  }
}

__global__ void fill_kernel(const int* __restrict__ rows, int* __restrict__ deg,
                            const int* __restrict__ ptr, int* __restrict__ eids,
                            int E) {
  int e = blockIdx.x * 256 + threadIdx.x;
  if (e >= E) return;
  int row = rows[e];
  int old = atomicSub(&deg[row], 1);
  eids[ptr[row] + old - 1] = e;
}

// ---------------- pack W into MFMA B-fragment layout (bf16) ----------------
// Wp[((r*8+ks)*NTI + ni)*512 + lane*8 + j] = W_r[k][n],
//   k = ks*32 + (lane>>4)*8 + j,  n = ni*16 + (lane&15)
// so a lane's b_frag is one coalesced 16B load.
__global__ void pack_w_kernel(const float* __restrict__ comps,
                              const float* __restrict__ bases,
                              unsigned short* __restrict__ Wp,
                              int NTI, int NTOT, int total) {
  int idx = blockIdx.x * 256 + threadIdx.x;
  if (idx >= total) return;
  int j = idx & 7;
  int lane = (idx >> 3) & 63;
  int ni = (idx >> 9) % NTI;
  int t = (idx >> 9) / NTI;        // r*8 + ks
  int ks = t & 7;
  int r = t >> 3;
  int k = ks * 32 + ((lane >> 4) << 3) + j;
  int n = ni * 16 + (lane & 15);
  float acc = 0.f;
#pragma unroll
  for (int b = 0; b < NB; ++b)
    acc += comps[r * NB + b] * bases[(size_t)b * 256 * NTOT + (size_t)k * NTOT + n];
  Wp[idx] = f2bf(acc);
}

// ---------------- gather one relation's 32-row tile into LDS (bf16, swizzled) ----------------
__device__ __forceinline__ void gather_rows(const float* __restrict__ vals,
                                            const int* __restrict__ cols,
                                            const int* __restrict__ eids,
                                            const int* __restrict__ ptr,
                                            const float* __restrict__ X,
                                            unsigned short* lds,
                                            int node0, int N, int r,
                                            int lane, int w) {
#pragma unroll 2
  for (int q = 0; q < 8; ++q) {
    int rr = w * 8 + q;              // row within 32-row tile
    int node = node0 + rr;
    float4 acc = make_float4(0.f, 0.f, 0.f, 0.f);
    if (node < N) {
      int g = r * N + node;
      int p0 = ptr[g], p1 = ptr[g + 1];
      for (int p = p0; p < p1; ++p) {
        int eid = eids[p];
        float v = vals[eid];
        float4 x = reinterpret_cast<const float4*>(X)[(size_t)cols[eid] * 64 + lane];
        acc.x += v * x.x;
        acc.y += v * x.y;
        acc.z += v * x.z;
        acc.w += v * x.w;
      }
    }
    ushort4 o;
    o.x = f2bf(acc.x); o.y = f2bf(acc.y); o.z = f2bf(acc.z); o.w = f2bf(acc.w);
    int boff = rr * 512 + lane * 8;
    boff ^= (rr & 7) << 4;           // XOR swizzle (matches reader)
    *reinterpret_cast<ushort4*>(reinterpret_cast<char*>(lds) + boff) = o;
  }
}

// ---------------- fused layer 1: out1 = relu(bias1 + sum_r (A_r X) W1_r) ----------------
// block: 32 rows; 4 waves; wave w owns cols [w*64, w*64+64)
__global__ __launch_bounds__(256, 4)
void fused_l1(const float* __restrict__ vals, const int* __restrict__ cols,
              const int* __restrict__ eids, const int* __restrict__ ptr,
              const float* __restrict__ X, const unsigned short* __restrict__ W1p,
              const float* __restrict__ bias1, float* __restrict__ out1, int N) {
  __shared__ unsigned short lds[32 * 256];
  const int w = threadIdx.x >> 6, lane = threadIdx.x & 63;
  const int node0 = blockIdx.x * 32;

  f32x4 acc[2][4];
#pragma unroll
  for (int mi = 0; mi < 2; ++mi)
#pragma unroll
    for (int ni = 0; ni < 4; ++ni) acc[mi][ni] = (f32x4)(0.f);

  for (int r = 0; r < REFF; ++r) {
    gather_rows(vals, cols, eids, ptr, X, lds, node0, N, r, lane, w);
    __syncthreads();
#pragma unroll 2
    for (int ks = 0; ks < 8; ++ks) {
      bf16x8 a[2];
#pragma unroll
      for (int mi = 0; mi < 2; ++mi) {
        int row = mi * 16 + (lane & 15);
        int boff = row * 512 + ks * 64 + ((lane >> 4) << 4);
        boff ^= (row & 7) << 4;
        a[mi] = *reinterpret_cast<const bf16x8*>(
            reinterpret_cast<const char*>(lds) + boff);
      }
#pragma unroll
      for (int ni = 0; ni < 4; ++ni) {
        int niG = w * 4 + ni;
        bf16x8 b = *reinterpret_cast<const bf16x8*>(
            W1p + (((size_t)(r * 8 + ks) * 16 + niG) << 9) + lane * 8);
#pragma unroll
        for (int mi = 0; mi < 2; ++mi)
          acc[mi][ni] = __builtin_amdgcn_mfma_f32_16x16x32_bf16(a[mi], b,
                                                               acc[mi][ni], 0, 0, 0);
      }
    }
    __syncthreads();
  }
  // epilogue: bias + relu, store fp32
#pragma unroll
  for (int mi = 0; mi < 2; ++mi) {
    int rbase = node0 + mi * 16 + ((lane >> 4) << 2);
#pragma unroll
    for (int ni = 0; ni < 4; ++ni) {
      int col = w * 64 + ni * 16 + (lane & 15);
      float bb = bias1[col];
#pragma unroll
      for (int reg = 0; reg < 4; ++reg) {
        int row = rbase + reg;
        if (row < N)
          out1[(size_t)row * 256 + col] = fmaxf(acc[mi][ni][reg] + bb, 0.f);
      }
    }
  }
}

// ---------------- fused layer 2: out = bias2 + sum_r (A_r out1) W2_r ----------------
// block: 32 rows; wave w: m-tile (w>>1), n-tile (w&1)
__global__ __launch_bounds__(256, 4)
void fused_l2(const float* __restrict__ vals, const int* __restrict__ cols,
              const int* __restrict__ eids, const int* __restrict__ ptr,
              const float* __restrict__ X, const unsigned short* __restrict__ W2p,
              const float* __restrict__ bias2, float* __restrict__ out, int N) {
  __shared__ unsigned short lds[32 * 256];
  const int w = threadIdx.x >> 6, lane = threadIdx.x & 63;
  const int node0 = blockIdx.x * 32;
  const int mi = w >> 1, ni = w & 1;

  f32x4 acc = (f32x4)(0.f);

  for (int r = 0; r < REFF; ++r) {
    gather_rows(vals, cols, eids, ptr, X, lds, node0, N, r, lane, w);
    __syncthreads();
#pragma unroll 2
    for (int ks = 0; ks < 8; ++ks) {
      int row = mi * 16 + (lane & 15);
      int boff = row * 512 + ks * 64 + ((lane >> 4) << 4);
      boff ^= (row & 7) << 4;
      bf16x8 a = *reinterpret_cast<const bf16x8*>(
          reinterpret_cast<const char*>(lds) + boff);
      bf16x8 b = *reinterpret_cast<const bf16x8*>(
          W2p + (((size_t)(r * 8 + ks) * 2 + ni) << 9) + lane * 8);
      acc = __builtin_amdgcn_mfma_f32_16x16x32_bf16(a, b, acc, 0, 0, 0);
    }
    __syncthreads();
  }
  int col = ni * 16 + (lane & 15);
  float bb = bias2[col];
  int rbase = node0 + mi * 16 + ((lane >> 4) << 2);
#pragma unroll
  for (int reg = 0; reg < 4; ++reg) {
    int row = rbase + reg;
    if (row < N) out[(size_t)row * 32 + col] = acc[reg] + bb;
  }
}

extern "C" void kernel_launch(void* const* d_in, const int* in_sizes, int n_in,
                              void* d_out, int out_size, void* d_ws, size_t ws_size,
                              hipStream_t stream) {
  const float* features = (const float*)d_in[0];
  const float* ver_vals = (const float*)d_in[1];
  const float* comps1   = (const float*)d_in[2];
  const float* bases1   = (const float*)d_in[3];
  const float* comps2   = (const float*)d_in[4];
  const float* bases2   = (const float*)d_in[5];
  const float* bias1    = (const float*)d_in[6];
  const float* bias2    = (const float*)d_in[7];
  const int* ver_rows   = (const int*)d_in[8];
  const int* ver_cols   = (const int*)d_in[9];

  const int N = in_sizes[0] / 256;   // 30000
  const int E = in_sizes[1];         // 500000
  const int NR = REFF * N;           // 270000
  const int NT = (NR + 1023) / 1024;

  // ---- workspace layout (~36 MB; 64.1 MB proven-safe) ----
  char* p = (char*)d_ws;
  float* out1 = (float*)p;                    p += (size_t)N * 256 * 4;       // 30.7 MB
  unsigned short* W1p = (unsigned short*)p;   p += (size_t)REFF * 65536 * 2;  // 1.18 MB
  unsigned short* W2p = (unsigned short*)p;   p += (size_t)REFF * 8192 * 2;   // 0.15 MB
  int* deg  = (int*)p;                        p += (size_t)NR * 4;
  int* ptr  = (int*)p;                        p += (size_t)(NR + 4) * 4;
  int* eids = (int*)p;                        p += (size_t)E * 4;
  int* bsum = (int*)p;                        p += 512 * 4;

  // ---- CSR build ----
  hipMemsetAsync(deg, 0, (size_t)NR * 4, stream);
  hist_kernel<<<(E + 255) / 256, 256, 0, stream>>>(ver_rows, deg, E);
  scan1_kernel<<<NT, 256, 0, stream>>>(deg, bsum, NR);
  scan2_kernel<<<1, 512, 0, stream>>>(bsum, ptr, NT, NR);
  scan3_kernel<<<NT, 256, 0, stream>>>(deg, bsum, ptr, NR);
  fill_kernel<<<(E + 255) / 256, 256, 0, stream>>>(ver_rows, deg, ptr, eids, E);

  // ---- packed weights ----
  pack_w_kernel<<<(REFF * 8 * 16 * 512) / 256, 256, 0, stream>>>(
      comps1, bases1, W1p, 16, 256, REFF * 8 * 16 * 512);
  pack_w_kernel<<<(REFF * 8 * 2 * 512) / 256, 256, 0, stream>>>(
      comps2, bases2, W2p, 2, 32, REFF * 8 * 2 * 512);

  const int nblk = (N + 31) / 32;   // 938

  fused_l1<<<nblk, 256, 0, stream>>>(ver_vals, ver_cols, eids, ptr, features,
                                     W1p, bias1, out1, N);
  fused_l2<<<nblk, 256, 0, stream>>>(ver_vals, ver_cols, eids, ptr, out1,
                                     W2p, bias2, (float*)d_out, N);
}

// Round 5
// 369.146 us; speedup vs baseline: 11.8920x; 1.4165x over previous
//
#include <hip/hip_runtime.h>

typedef __attribute__((ext_vector_type(8))) short bf16x8;
typedef __attribute__((ext_vector_type(4))) float f32x4;

constexpr int NB = 16;    // bases
constexpr int REFF = 9;   // relations

struct alignas(8) EPair { float v; int c; };

__device__ __forceinline__ unsigned short f2bf(float f) {
  unsigned u = __float_as_uint(f);
  u += 0x7FFFu + ((u >> 16) & 1u);          // round-to-nearest-even
  return (unsigned short)(u >> 16);
}
__device__ __forceinline__ float bf2f(short s) {
  return __uint_as_float(((unsigned)(unsigned short)s) << 16);
}

// ---------------- dual histogram: deg1 over g=r*N+dst, deg2 over dst ----------------
__global__ void hist_both_kernel(const int* __restrict__ rows,
                                 int* __restrict__ deg1, int* __restrict__ deg2,
                                 int E, int N) {
  int e = blockIdx.x * 256 + threadIdx.x;
  if (e >= E) return;
  int g = rows[e];
  atomicAdd(&deg1[g], 1);
  atomicAdd(&deg2[g % N], 1);
}

// ---------------- scan kernels (generic over NR) ----------------
__global__ void scan1_kernel(const int* __restrict__ deg, int* __restrict__ bsum,
                             int NR) {
  __shared__ int s[256];
  int t = threadIdx.x;
  int base = blockIdx.x * 1024 + t * 4;
  int acc = 0;
#pragma unroll
  for (int q = 0; q < 4; ++q)
    if (base + q < NR) acc += deg[base + q];
  s[t] = acc;
  __syncthreads();
  for (int off = 128; off > 0; off >>= 1) {
    if (t < off) s[t] += s[t + off];
    __syncthreads();
  }
  if (t == 0) bsum[blockIdx.x] = s[0];
}

__global__ void scan2_kernel(int* __restrict__ bsum, int* __restrict__ ptr,
                             int NT, int NR) {
  __shared__ int s[512];
  int t = threadIdx.x;
  int v = (t < NT) ? bsum[t] : 0;
  s[t] = v;
  __syncthreads();
  for (int off = 1; off < 512; off <<= 1) {
    int x = (t >= off) ? s[t - off] : 0;
    __syncthreads();
    s[t] += x;
    __syncthreads();
  }
  if (t < NT) bsum[t] = s[t] - v;
  if (t == NT - 1) ptr[NR] = s[t];
}

__global__ void scan3_kernel(const int* __restrict__ deg,
                             const int* __restrict__ bsum,
                             int* __restrict__ ptr, int NR) {
  __shared__ int s[256];
  int t = threadIdx.x;
  int base = blockIdx.x * 1024 + t * 4;
  int d[4];
#pragma unroll
  for (int q = 0; q < 4; ++q)
    d[q] = (base + q < NR) ? deg[base + q] : 0;
  int tsum = d[0] + d[1] + d[2] + d[3];
  s[t] = tsum;
  __syncthreads();
  for (int off = 1; off < 256; off <<= 1) {
    int x = (t >= off) ? s[t - off] : 0;
    __syncthreads();
    s[t] += x;
    __syncthreads();
  }
  int off0 = bsum[blockIdx.x] + s[t] - tsum;
#pragma unroll
  for (int q = 0; q < 4; ++q) {
    if (base + q < NR) ptr[base + q] = off0;
    off0 += d[q];
  }
}

// fill both CSRs with inline (val, col) payloads; deg arrays consumed as cursors
__global__ void fill_both_kernel(const int* __restrict__ rows,
                                 const int* __restrict__ cols,
                                 const float* __restrict__ vals,
                                 int* __restrict__ deg1, const int* __restrict__ ptr1,
                                 EPair* __restrict__ pay1,
                                 int* __restrict__ deg2, const int* __restrict__ ptr2,
                                 EPair* __restrict__ pay2, int E, int N) {
  int e = blockIdx.x * 256 + threadIdx.x;
  if (e >= E) return;
  int g = rows[e];
  int src = cols[e];
  float v = vals[e];
  int o1 = atomicSub(&deg1[g], 1);
  EPair p1v; p1v.v = v; p1v.c = src;
  pay1[ptr1[g] + o1 - 1] = p1v;
  int dst = g % N;
  int o2 = atomicSub(&deg2[dst], 1);
  EPair p2v; p2v.v = v; p2v.c = g - dst + src;   // r*N + src
  pay2[ptr2[dst] + o2 - 1] = p2v;
}

// ---------------- fp32 -> bf16 convert ----------------
__global__ void cvt_bf16_kernel(const float* __restrict__ in,
                                unsigned short* __restrict__ out, int n4) {
  int i = blockIdx.x * 256 + threadIdx.x;
  if (i >= n4) return;
  float4 f = reinterpret_cast<const float4*>(in)[i];
  ushort4 o;
  o.x = f2bf(f.x); o.y = f2bf(f.y); o.z = f2bf(f.z); o.w = f2bf(f.w);
  reinterpret_cast<ushort4*>(out)[i] = o;
}

// ---------------- pack W into MFMA B-fragment layout (bf16) ----------------
__global__ void pack_w_kernel(const float* __restrict__ comps,
                              const float* __restrict__ bases,
                              unsigned short* __restrict__ Wp,
                              int NTI, int NTOT, int total) {
  int idx = blockIdx.x * 256 + threadIdx.x;
  if (idx >= total) return;
  int j = idx & 7;
  int lane = (idx >> 3) & 63;
  int ni = (idx >> 9) % NTI;
  int t = (idx >> 9) / NTI;        // r*8 + ks
  int ks = t & 7;
  int r = t >> 3;
  int k = ks * 32 + ((lane >> 4) << 3) + j;
  int n = ni * 16 + (lane & 15);
  float acc = 0.f;
#pragma unroll
  for (int b = 0; b < NB; ++b)
    acc += comps[r * NB + b] * bases[(size_t)b * 256 * NTOT + (size_t)k * NTOT + n];
  Wp[idx] = f2bf(acc);
}

// ---------------- gather one relation's 32-row tile into LDS (bf16, swizzled) ----------------
// half-wave h=lane>>5 takes edges p0+2i+h; lane covers cols (lane&31)*8..+7
__device__ __forceinline__ void gather_rows_bf(const EPair* __restrict__ pay,
                                               const int* __restrict__ ptr,
                                               const unsigned short* __restrict__ Xbf,
                                               unsigned short* lds,
                                               int node0, int N, int r,
                                               int lane, int w) {
  const int h = lane >> 5;
  const int cl = lane & 31;
  for (int q = 0; q < 8; ++q) {
    int rr = w * 8 + q;              // row within 32-row tile
    int node = node0 + rr;
    float acc[8];
#pragma unroll
    for (int j = 0; j < 8; ++j) acc[j] = 0.f;
    if (node < N) {
      int g = r * N + node;
      int p0 = ptr[g], p1 = ptr[g + 1];
      int p = p0 + h;
      EPair e;
      if (p < p1) e = pay[p];
      while (p < p1) {
        EPair cur = e;
        if (p + 2 < p1) e = pay[p + 2];
        bf16x8 x = *reinterpret_cast<const bf16x8*>(Xbf + (size_t)cur.c * 256 + cl * 8);
#pragma unroll
        for (int j = 0; j < 8; ++j) acc[j] += cur.v * bf2f(x[j]);
        p += 2;
      }
    }
    // combine halves, lanes 0..31 store 16B
#pragma unroll
    for (int j = 0; j < 8; ++j) acc[j] += __shfl_xor(acc[j], 32);
    if (lane < 32) {
      uint4 o;
      o.x = (unsigned)f2bf(acc[0]) | ((unsigned)f2bf(acc[1]) << 16);
      o.y = (unsigned)f2bf(acc[2]) | ((unsigned)f2bf(acc[3]) << 16);
      o.z = (unsigned)f2bf(acc[4]) | ((unsigned)f2bf(acc[5]) << 16);
      o.w = (unsigned)f2bf(acc[6]) | ((unsigned)f2bf(acc[7]) << 16);
      int boff = rr * 512 + lane * 16;
      boff ^= (rr & 7) << 4;           // XOR swizzle (matches reader)
      *reinterpret_cast<uint4*>(reinterpret_cast<char*>(lds) + boff) = o;
    }
  }
}

// ---------------- fused layer 1: out1bf = bf16(relu(bias1 + sum_r (A_r X) W1_r)) ----------------
__global__ __launch_bounds__(256, 6)
void fused_l1(const EPair* __restrict__ pay1, const int* __restrict__ ptr1,
              const unsigned short* __restrict__ Xbf,
              const unsigned short* __restrict__ W1p,
              const float* __restrict__ bias1,
              unsigned short* __restrict__ out1bf, int N) {
  __shared__ unsigned short lds[32 * 256];
  const int w = threadIdx.x >> 6, lane = threadIdx.x & 63;
  const int node0 = blockIdx.x * 32;

  f32x4 acc[2][4];
#pragma unroll
  for (int mi = 0; mi < 2; ++mi)
#pragma unroll
    for (int ni = 0; ni < 4; ++ni) acc[mi][ni] = (f32x4)(0.f);

  for (int r = 0; r < REFF; ++r) {
    gather_rows_bf(pay1, ptr1, Xbf, lds, node0, N, r, lane, w);
    __syncthreads();
#pragma unroll 2
    for (int ks = 0; ks < 8; ++ks) {
      bf16x8 a[2];
#pragma unroll
      for (int mi = 0; mi < 2; ++mi) {
        int row = mi * 16 + (lane & 15);
        int boff = row * 512 + ks * 64 + ((lane >> 4) << 4);
        boff ^= (row & 7) << 4;
        a[mi] = *reinterpret_cast<const bf16x8*>(
            reinterpret_cast<const char*>(lds) + boff);
      }
#pragma unroll
      for (int ni = 0; ni < 4; ++ni) {
        int niG = w * 4 + ni;
        bf16x8 b = *reinterpret_cast<const bf16x8*>(
            W1p + (((size_t)(r * 8 + ks) * 16 + niG) << 9) + lane * 8);
#pragma unroll
        for (int mi = 0; mi < 2; ++mi)
          acc[mi][ni] = __builtin_amdgcn_mfma_f32_16x16x32_bf16(a[mi], b,
                                                               acc[mi][ni], 0, 0, 0);
      }
    }
    __syncthreads();
  }
#pragma unroll
  for (int mi = 0; mi < 2; ++mi) {
    int rbase = node0 + mi * 16 + ((lane >> 4) << 2);
#pragma unroll
    for (int ni = 0; ni < 4; ++ni) {
      int col = w * 64 + ni * 16 + (lane & 15);
      float bb = bias1[col];
#pragma unroll
      for (int reg = 0; reg < 4; ++reg) {
        int row = rbase + reg;
        if (row < N)
          out1bf[(size_t)row * 256 + col] = f2bf(fmaxf(acc[mi][ni][reg] + bb, 0.f));
      }
    }
  }
}

// ---------------- layer 2 GEMM: Y2[r][n][c] = out1bf[n] @ W2_r, bf16 out ----------------
// 4 waves, wave w owns rows m0+w*16..+15; all 9 relations accumulated in regs
__global__ void gemm_l2(const unsigned short* __restrict__ out1bf,
                        const unsigned short* __restrict__ W2p,
                        unsigned short* __restrict__ Y2, int N) {
  const int w = threadIdx.x >> 6, lane = threadIdx.x & 63;
  const int m0 = blockIdx.x * 64 + w * 16;
  int arow = m0 + (lane & 15);
  if (arow >= N) arow = N - 1;
  const unsigned short* abase = out1bf + (size_t)arow * 256 + ((lane >> 4) << 3);

  f32x4 acc[REFF][2];
#pragma unroll
  for (int r = 0; r < REFF; ++r)
#pragma unroll
    for (int ni = 0; ni < 2; ++ni) acc[r][ni] = (f32x4)(0.f);

#pragma unroll
  for (int ks = 0; ks < 8; ++ks) {
    bf16x8 a = *reinterpret_cast<const bf16x8*>(abase + ks * 32);
#pragma unroll
    for (int r = 0; r < REFF; ++r)
#pragma unroll
      for (int ni = 0; ni < 2; ++ni) {
        bf16x8 b = *reinterpret_cast<const bf16x8*>(
            W2p + (((size_t)(r * 8 + ks) * 2 + ni) << 9) + lane * 8);
        acc[r][ni] = __builtin_amdgcn_mfma_f32_16x16x32_bf16(a, b, acc[r][ni], 0, 0, 0);
      }
  }
  const int col = lane & 15;
  const int rbase = m0 + ((lane >> 4) << 2);
#pragma unroll
  for (int r = 0; r < REFF; ++r)
#pragma unroll
    for (int ni = 0; ni < 2; ++ni)
#pragma unroll
      for (int reg = 0; reg < 4; ++reg) {
        int row = rbase + reg;
        if (row < N)
          Y2[((size_t)r * N + row) * 32 + ni * 16 + col] = f2bf(acc[r][ni][reg]);
      }
}

// ---------------- layer 2 gather: out[n] = bias2 + sum_edges val * Y2[ycol] ----------------
// quarter-wave (16 lanes) per output row; lane covers cols 2c..2c+1
__global__ void gather_out_kernel(const EPair* __restrict__ pay2,
                                  const int* __restrict__ ptr2,
                                  const unsigned short* __restrict__ Y2,
                                  const float* __restrict__ bias2,
                                  float* __restrict__ out, int N) {
  int qw = threadIdx.x >> 4;
  int c = threadIdx.x & 15;
  int n = blockIdx.x * 16 + qw;
  if (n >= N) return;
  int p0 = ptr2[n], p1 = ptr2[n + 1];
  float ax = 0.f, ay = 0.f;
  EPair e;
  if (p0 < p1) e = pay2[p0];
  for (int p = p0; p < p1; ++p) {
    EPair cur = e;
    if (p + 1 < p1) e = pay2[p + 1];
    unsigned u = *reinterpret_cast<const unsigned*>(Y2 + (size_t)cur.c * 32 + c * 2);
    ax += cur.v * __uint_as_float(u << 16);
    ay += cur.v * __uint_as_float(u & 0xFFFF0000u);
  }
  float2 o;
  o.x = ax + bias2[c * 2];
  o.y = ay + bias2[c * 2 + 1];
  reinterpret_cast<float2*>(out)[(size_t)n * 16 + c] = o;
}

extern "C" void kernel_launch(void* const* d_in, const int* in_sizes, int n_in,
                              void* d_out, int out_size, void* d_ws, size_t ws_size,
                              hipStream_t stream) {
  const float* features = (const float*)d_in[0];
  const float* ver_vals = (const float*)d_in[1];
  const float* comps1   = (const float*)d_in[2];
  const float* bases1   = (const float*)d_in[3];
  const float* comps2   = (const float*)d_in[4];
  const float* bases2   = (const float*)d_in[5];
  const float* bias1    = (const float*)d_in[6];
  const float* bias2    = (const float*)d_in[7];
  const int* ver_rows   = (const int*)d_in[8];
  const int* ver_cols   = (const int*)d_in[9];

  const int N = in_sizes[0] / 256;   // 30000
  const int E = in_sizes[1];         // 500000
  const int NR = REFF * N;           // 270000
  const int NT1 = (NR + 1023) / 1024;
  const int NT2 = (N + 1023) / 1024;

  // ---- workspace layout (~57 MB; 64.1 MB proven-safe) ----
  char* p = (char*)d_ws;
  unsigned short* Xbf    = (unsigned short*)p; p += (size_t)N * 256 * 2;       // 15.36 MB
  unsigned short* out1bf = (unsigned short*)p; p += (size_t)N * 256 * 2;       // 15.36 MB
  unsigned short* Y2     = (unsigned short*)p; p += (size_t)REFF * N * 32 * 2; // 17.28 MB
  unsigned short* W1p    = (unsigned short*)p; p += (size_t)REFF * 65536 * 2;  // 1.18 MB
  unsigned short* W2p    = (unsigned short*)p; p += (size_t)REFF * 8192 * 2;   // 0.15 MB
  int* deg1 = (int*)p;   p += (size_t)NR * 4;
  int* ptr1 = (int*)p;   p += (size_t)(NR + 4) * 4;
  EPair* pay1 = (EPair*)p; p += (size_t)E * 8;
  int* deg2 = (int*)p;   p += (size_t)N * 4;
  int* ptr2 = (int*)p;   p += (size_t)(N + 4) * 4;
  EPair* pay2 = (EPair*)p; p += (size_t)E * 8;
  int* bsum = (int*)p;   p += 512 * 4;

  // ---- dual CSR build ----
  hipMemsetAsync(deg1, 0, (size_t)NR * 4, stream);
  hipMemsetAsync(deg2, 0, (size_t)N * 4, stream);
  hist_both_kernel<<<(E + 255) / 256, 256, 0, stream>>>(ver_rows, deg1, deg2, E, N);
  scan1_kernel<<<NT1, 256, 0, stream>>>(deg1, bsum, NR);
  scan2_kernel<<<1, 512, 0, stream>>>(bsum, ptr1, NT1, NR);
  scan3_kernel<<<NT1, 256, 0, stream>>>(deg1, bsum, ptr1, NR);
  scan1_kernel<<<NT2, 256, 0, stream>>>(deg2, bsum, N);
  scan2_kernel<<<1, 512, 0, stream>>>(bsum, ptr2, NT2, N);
  scan3_kernel<<<NT2, 256, 0, stream>>>(deg2, bsum, ptr2, N);
  fill_both_kernel<<<(E + 255) / 256, 256, 0, stream>>>(
      ver_rows, ver_cols, ver_vals, deg1, ptr1, pay1, deg2, ptr2, pay2, E, N);

  // ---- converts & packed weights ----
  cvt_bf16_kernel<<<(N * 64 + 255) / 256, 256, 0, stream>>>(features, Xbf, N * 64);
  pack_w_kernel<<<(REFF * 8 * 16 * 512) / 256, 256, 0, stream>>>(
      comps1, bases1, W1p, 16, 256, REFF * 8 * 16 * 512);
  pack_w_kernel<<<(REFF * 8 * 2 * 512) / 256, 256, 0, stream>>>(
      comps2, bases2, W2p, 2, 32, REFF * 8 * 2 * 512);

  // ---- layer 1 ----
  fused_l1<<<(N + 31) / 32, 256, 0, stream>>>(pay1, ptr1, Xbf, W1p, bias1,
                                              out1bf, N);
  // ---- layer 2: transform-first ----
  gemm_l2<<<(N + 63) / 64, 256, 0, stream>>>(out1bf, W2p, Y2, N);
  gather_out_kernel<<<(N + 15) / 16, 256, 0, stream>>>(pay2, ptr2, Y2, bias2,
                                                       (float*)d_out, N);
}

// Round 6
// 265.157 us; speedup vs baseline: 16.5558x; 1.3922x over previous
//
#include <hip/hip_runtime.h>

typedef __attribute__((ext_vector_type(8))) short bf16x8;
typedef __attribute__((ext_vector_type(4))) float f32x4;

constexpr int NB = 16;    // bases
constexpr int REFF = 9;   // relations

struct alignas(8) EPair { float v; int c; };

__device__ __forceinline__ unsigned short f2bf(float f) {
  unsigned u = __float_as_uint(f);
  u += 0x7FFFu + ((u >> 16) & 1u);          // round-to-nearest-even
  return (unsigned short)(u >> 16);
}
__device__ __forceinline__ float bf2f(short s) {
  return __uint_as_float(((unsigned)(unsigned short)s) << 16);
}

// ---------------- dual histogram: deg1 over g=r*N+dst, deg2 over dst ----------------
__global__ void hist_both_kernel(const int* __restrict__ rows,
                                 int* __restrict__ deg1, int* __restrict__ deg2,
                                 int E, int N) {
  int e = blockIdx.x * 256 + threadIdx.x;
  if (e >= E) return;
  int g = rows[e];
  atomicAdd(&deg1[g], 1);
  atomicAdd(&deg2[g % N], 1);
}

// ---------------- merged scan kernels (both CSRs in one launch) ----------------
__global__ void scan1_both(const int* __restrict__ deg1, int* __restrict__ bsum1,
                           int NR1, int NT1,
                           const int* __restrict__ deg2, int* __restrict__ bsum2,
                           int NR2) {
  const int* deg; int* bsum; int NR, b;
  if ((int)blockIdx.x < NT1) { deg = deg1; bsum = bsum1; NR = NR1; b = blockIdx.x; }
  else { deg = deg2; bsum = bsum2; NR = NR2; b = blockIdx.x - NT1; }
  __shared__ int s[256];
  int t = threadIdx.x;
  int base = b * 1024 + t * 4;
  int acc = 0;
#pragma unroll
  for (int q = 0; q < 4; ++q)
    if (base + q < NR) acc += deg[base + q];
  s[t] = acc;
  __syncthreads();
  for (int off = 128; off > 0; off >>= 1) {
    if (t < off) s[t] += s[t + off];
    __syncthreads();
  }
  if (t == 0) bsum[b] = s[0];
}

__global__ void scan2_both(int* __restrict__ bsum1, int* __restrict__ ptr1,
                           int NT1, int NR1,
                           int* __restrict__ bsum2, int* __restrict__ ptr2,
                           int NT2, int NR2) {
  int* bsum; int* ptr; int NT, NR;
  if (blockIdx.x == 0) { bsum = bsum1; ptr = ptr1; NT = NT1; NR = NR1; }
  else { bsum = bsum2; ptr = ptr2; NT = NT2; NR = NR2; }
  __shared__ int s[512];
  int t = threadIdx.x;
  int v = (t < NT) ? bsum[t] : 0;
  s[t] = v;
  __syncthreads();
  for (int off = 1; off < 512; off <<= 1) {
    int x = (t >= off) ? s[t - off] : 0;
    __syncthreads();
    s[t] += x;
    __syncthreads();
  }
  if (t < NT) bsum[t] = s[t] - v;
  if (t == NT - 1) ptr[NR] = s[t];
}

__global__ void scan3_both(const int* __restrict__ deg1, const int* __restrict__ bsum1,
                           int* __restrict__ ptr1, int NR1, int NT1,
                           const int* __restrict__ deg2, const int* __restrict__ bsum2,
                           int* __restrict__ ptr2, int NR2) {
  const int* deg; const int* bsum; int* ptr; int NR, b;
  if ((int)blockIdx.x < NT1) { deg = deg1; bsum = bsum1; ptr = ptr1; NR = NR1; b = blockIdx.x; }
  else { deg = deg2; bsum = bsum2; ptr = ptr2; NR = NR2; b = blockIdx.x - NT1; }
  __shared__ int s[256];
  int t = threadIdx.x;
  int base = b * 1024 + t * 4;
  int d[4];
#pragma unroll
  for (int q = 0; q < 4; ++q)
    d[q] = (base + q < NR) ? deg[base + q] : 0;
  int tsum = d[0] + d[1] + d[2] + d[3];
  s[t] = tsum;
  __syncthreads();
  for (int off = 1; off < 256; off <<= 1) {
    int x = (t >= off) ? s[t - off] : 0;
    __syncthreads();
    s[t] += x;
    __syncthreads();
  }
  int off0 = bsum[b] + s[t] - tsum;
#pragma unroll
  for (int q = 0; q < 4; ++q) {
    if (base + q < NR) ptr[base + q] = off0;
    off0 += d[q];
  }
}

// fill both CSRs with inline (val, col) payloads; deg arrays consumed as cursors
__global__ void fill_both_kernel(const int* __restrict__ rows,
                                 const int* __restrict__ cols,
                                 const float* __restrict__ vals,
                                 int* __restrict__ deg1, const int* __restrict__ ptr1,
                                 EPair* __restrict__ pay1,
                                 int* __restrict__ deg2, const int* __restrict__ ptr2,
                                 EPair* __restrict__ pay2, int E, int N) {
  int e = blockIdx.x * 256 + threadIdx.x;
  if (e >= E) return;
  int g = rows[e];
  int src = cols[e];
  float v = vals[e];
  int o1 = atomicSub(&deg1[g], 1);
  EPair p1v; p1v.v = v; p1v.c = src;
  pay1[ptr1[g] + o1 - 1] = p1v;
  int dst = g % N;
  int o2 = atomicSub(&deg2[dst], 1);
  EPair p2v; p2v.v = v; p2v.c = g - dst + src;   // r*N + src
  pay2[ptr2[dst] + o2 - 1] = p2v;
}

// ---------------- merged prep: features->bf16, pack W1, pack W2 ----------------
__device__ __forceinline__ unsigned short pack_w_one(const float* __restrict__ comps,
                                                     const float* __restrict__ bases,
                                                     int idx, int NTI, int NTOT) {
  int j = idx & 7;
  int lane = (idx >> 3) & 63;
  int ni = (idx >> 9) % NTI;
  int t = (idx >> 9) / NTI;        // r*8 + ks
  int ks = t & 7;
  int r = t >> 3;
  int k = ks * 32 + ((lane >> 4) << 3) + j;
  int n = ni * 16 + (lane & 15);
  float acc = 0.f;
#pragma unroll
  for (int b = 0; b < NB; ++b)
    acc += comps[r * NB + b] * bases[(size_t)b * 256 * NTOT + (size_t)k * NTOT + n];
  return f2bf(acc);
}

__global__ void prep_kernel(const float* __restrict__ features,
                            unsigned short* __restrict__ Xbf,
                            const float* __restrict__ comps1,
                            const float* __restrict__ bases1,
                            unsigned short* __restrict__ W1p,
                            const float* __restrict__ comps2,
                            const float* __restrict__ bases2,
                            unsigned short* __restrict__ W2p, int N) {
  const int n4 = N * 64;
  const int PW1 = REFF * 8 * 16 * 512;   // 589824
  const int PW2 = REFF * 8 * 2 * 512;    // 73728
  int idx = blockIdx.x * 256 + threadIdx.x;
  if (idx < n4) {
    float4 f = reinterpret_cast<const float4*>(features)[idx];
    ushort4 o;
    o.x = f2bf(f.x); o.y = f2bf(f.y); o.z = f2bf(f.z); o.w = f2bf(f.w);
    reinterpret_cast<ushort4*>(Xbf)[idx] = o;
  } else if (idx < n4 + PW1) {
    int i = idx - n4;
    W1p[i] = pack_w_one(comps1, bases1, i, 16, 256);
  } else if (idx < n4 + PW1 + PW2) {
    int i = idx - n4 - PW1;
    W2p[i] = pack_w_one(comps2, bases2, i, 2, 32);
  }
}

// ---------------- gather: half-wave owns a whole row (512B) ----------------
__device__ __forceinline__ void gather_rows_bf(const EPair* __restrict__ pay,
                                               const int* __restrict__ ptr,
                                               const unsigned short* __restrict__ Xbf,
                                               unsigned short* lds,
                                               int node0, int N, int r,
                                               int unit, int cl) {
#pragma unroll
  for (int q = 0; q < 2; ++q) {
    int rr = unit * 2 + q;              // row within 32-row tile
    int node = node0 + rr;
    float acc[8];
#pragma unroll
    for (int j = 0; j < 8; ++j) acc[j] = 0.f;
    if (node < N) {
      int g = r * N + node;
      int p0 = ptr[g], p1 = ptr[g + 1];
      EPair e;
      if (p0 < p1) e = pay[p0];
      for (int p = p0; p < p1; ++p) {
        EPair cur = e;
        if (p + 1 < p1) e = pay[p + 1];
        bf16x8 x = *reinterpret_cast<const bf16x8*>(Xbf + (size_t)cur.c * 256 + cl * 8);
#pragma unroll
        for (int j = 0; j < 8; ++j) acc[j] += cur.v * bf2f(x[j]);
      }
    }
    uint4 o;
    o.x = (unsigned)f2bf(acc[0]) | ((unsigned)f2bf(acc[1]) << 16);
    o.y = (unsigned)f2bf(acc[2]) | ((unsigned)f2bf(acc[3]) << 16);
    o.z = (unsigned)f2bf(acc[4]) | ((unsigned)f2bf(acc[5]) << 16);
    o.w = (unsigned)f2bf(acc[6]) | ((unsigned)f2bf(acc[7]) << 16);
    int boff = rr * 512 + cl * 16;
    boff ^= (rr & 7) << 4;              // XOR swizzle (matches reader)
    *reinterpret_cast<uint4*>(reinterpret_cast<char*>(lds) + boff) = o;
  }
}

// ---------------- fused layer 1: out1bf = bf16(relu(bias1 + sum_r (A_r X) W1_r)) ----------------
// 512 threads = 8 waves; 32-row tile; wave w owns cols [w*32, w*32+32)
__global__ __launch_bounds__(512, 8)
void fused_l1(const EPair* __restrict__ pay1, const int* __restrict__ ptr1,
              const unsigned short* __restrict__ Xbf,
              const unsigned short* __restrict__ W1p,
              const float* __restrict__ bias1,
              unsigned short* __restrict__ out1bf, int N) {
  __shared__ unsigned short lds[32 * 256];
  const int w = threadIdx.x >> 6, lane = threadIdx.x & 63;
  const int unit = threadIdx.x >> 5, cl = threadIdx.x & 31;
  const int node0 = blockIdx.x * 32;

  f32x4 acc[2][2];
#pragma unroll
  for (int mi = 0; mi < 2; ++mi)
#pragma unroll
    for (int ni = 0; ni < 2; ++ni) acc[mi][ni] = (f32x4)(0.f);

  for (int r = 0; r < REFF; ++r) {
    gather_rows_bf(pay1, ptr1, Xbf, lds, node0, N, r, unit, cl);
    __syncthreads();
#pragma unroll 2
    for (int ks = 0; ks < 8; ++ks) {
      bf16x8 a[2];
#pragma unroll
      for (int mi = 0; mi < 2; ++mi) {
        int row = mi * 16 + (lane & 15);
        int boff = row * 512 + ks * 64 + ((lane >> 4) << 4);
        boff ^= (row & 7) << 4;
        a[mi] = *reinterpret_cast<const bf16x8*>(
            reinterpret_cast<const char*>(lds) + boff);
      }
#pragma unroll
      for (int ni = 0; ni < 2; ++ni) {
        int niG = w * 2 + ni;
        bf16x8 b = *reinterpret_cast<const bf16x8*>(
            W1p + (((size_t)(r * 8 + ks) * 16 + niG) << 9) + lane * 8);
#pragma unroll
        for (int mi = 0; mi < 2; ++mi)
          acc[mi][ni] = __builtin_amdgcn_mfma_f32_16x16x32_bf16(a[mi], b,
                                                               acc[mi][ni], 0, 0, 0);
      }
    }
    __syncthreads();
  }
#pragma unroll
  for (int mi = 0; mi < 2; ++mi) {
    int rbase = node0 + mi * 16 + ((lane >> 4) << 2);
#pragma unroll
    for (int ni = 0; ni < 2; ++ni) {
      int col = (w * 2 + ni) * 16 + (lane & 15);
      float bb = bias1[col];
#pragma unroll
      for (int reg = 0; reg < 4; ++reg) {
        int row = rbase + reg;
        if (row < N)
          out1bf[(size_t)row * 256 + col] = f2bf(fmaxf(acc[mi][ni][reg] + bb, 0.f));
      }
    }
  }
}

// ---------------- layer 2 GEMM: Y2[r][n][c] = out1bf[n] @ W2_r, bf16 out ----------------
__global__ void gemm_l2(const unsigned short* __restrict__ out1bf,
                        const unsigned short* __restrict__ W2p,
                        unsigned short* __restrict__ Y2, int N) {
  const int w = threadIdx.x >> 6, lane = threadIdx.x & 63;
  const int m0 = blockIdx.x * 64 + w * 16;
  int arow = m0 + (lane & 15);
  if (arow >= N) arow = N - 1;
  const unsigned short* abase = out1bf + (size_t)arow * 256 + ((lane >> 4) << 3);

  f32x4 acc[REFF][2];
#pragma unroll
  for (int r = 0; r < REFF; ++r)
#pragma unroll
    for (int ni = 0; ni < 2; ++ni) acc[r][ni] = (f32x4)(0.f);

#pragma unroll
  for (int ks = 0; ks < 8; ++ks) {
    bf16x8 a = *reinterpret_cast<const bf16x8*>(abase + ks * 32);
#pragma unroll
    for (int r = 0; r < REFF; ++r)
#pragma unroll
      for (int ni = 0; ni < 2; ++ni) {
        bf16x8 b = *reinterpret_cast<const bf16x8*>(
            W2p + (((size_t)(r * 8 + ks) * 2 + ni) << 9) + lane * 8);
        acc[r][ni] = __builtin_amdgcn_mfma_f32_16x16x32_bf16(a, b, acc[r][ni], 0, 0, 0);
      }
  }
  const int col = lane & 15;
  const int rbase = m0 + ((lane >> 4) << 2);
#pragma unroll
  for (int r = 0; r < REFF; ++r)
#pragma unroll
    for (int ni = 0; ni < 2; ++ni)
#pragma unroll
      for (int reg = 0; reg < 4; ++reg) {
        int row = rbase + reg;
        if (row < N)
          Y2[((size_t)r * N + row) * 32 + ni * 16 + col] = f2bf(acc[r][ni][reg]);
      }
}

// ---------------- layer 2 gather: half-wave per node, parity-split edges ----------------
__global__ void gather_out_kernel(const EPair* __restrict__ pay2,
                                  const int* __restrict__ ptr2,
                                  const unsigned short* __restrict__ Y2,
                                  const float* __restrict__ bias2,
                                  float* __restrict__ out, int N) {
  int hw = threadIdx.x >> 5;           // 8 half-waves per block
  int lane = threadIdx.x & 31;
  int c = lane & 15, h = lane >> 4;
  int n = blockIdx.x * 8 + hw;
  if (n >= N) return;
  int p0 = ptr2[n], p1 = ptr2[n + 1];
  float ax = 0.f, ay = 0.f;
  int p = p0 + h;
  EPair e;
  if (p < p1) e = pay2[p];
  while (p < p1) {
    EPair cur = e;
    if (p + 2 < p1) e = pay2[p + 2];
    unsigned u = *reinterpret_cast<const unsigned*>(Y2 + (size_t)cur.c * 32 + c * 2);
    ax += cur.v * __uint_as_float(u << 16);
    ay += cur.v * __uint_as_float(u & 0xFFFF0000u);
    p += 2;
  }
  ax += __shfl_xor(ax, 16);
  ay += __shfl_xor(ay, 16);
  if (h == 0) {
    float2 o;
    o.x = ax + bias2[c * 2];
    o.y = ay + bias2[c * 2 + 1];
    reinterpret_cast<float2*>(out)[(size_t)n * 16 + c] = o;
  }
}

extern "C" void kernel_launch(void* const* d_in, const int* in_sizes, int n_in,
                              void* d_out, int out_size, void* d_ws, size_t ws_size,
                              hipStream_t stream) {
  const float* features = (const float*)d_in[0];
  const float* ver_vals = (const float*)d_in[1];
  const float* comps1   = (const float*)d_in[2];
  const float* bases1   = (const float*)d_in[3];
  const float* comps2   = (const float*)d_in[4];
  const float* bases2   = (const float*)d_in[5];
  const float* bias1    = (const float*)d_in[6];
  const float* bias2    = (const float*)d_in[7];
  const int* ver_rows   = (const int*)d_in[8];
  const int* ver_cols   = (const int*)d_in[9];

  const int N = in_sizes[0] / 256;   // 30000
  const int E = in_sizes[1];         // 500000
  const int NR = REFF * N;           // 270000
  const int NT1 = (NR + 1023) / 1024;
  const int NT2 = (N + 1023) / 1024;

  // ---- workspace layout (~60 MB; 64.1 MB proven-safe) ----
  char* p = (char*)d_ws;
  unsigned short* Xbf    = (unsigned short*)p; p += (size_t)N * 256 * 2;       // 15.36 MB
  unsigned short* out1bf = (unsigned short*)p; p += (size_t)N * 256 * 2;       // 15.36 MB
  unsigned short* Y2     = (unsigned short*)p; p += (size_t)REFF * N * 32 * 2; // 17.28 MB
  unsigned short* W1p    = (unsigned short*)p; p += (size_t)REFF * 65536 * 2;  // 1.18 MB
  unsigned short* W2p    = (unsigned short*)p; p += (size_t)REFF * 8192 * 2;   // 0.15 MB
  int* ptr1 = (int*)p;     p += (size_t)(NR + 4) * 4;
  int* ptr2 = (int*)p;     p += (size_t)(N + 4) * 4;
  EPair* pay1 = (EPair*)p; p += (size_t)E * 8;
  EPair* pay2 = (EPair*)p; p += (size_t)E * 8;
  int* deg1 = (int*)p;     p += (size_t)NR * 4;   // deg1+deg2 contiguous: one memset
  int* deg2 = (int*)p;     p += (size_t)N * 4;
  int* bsum1 = (int*)p;    p += 512 * 4;
  int* bsum2 = (int*)p;    p += 512 * 4;

  // ---- CSR build (both keys) ----
  hipMemsetAsync(deg1, 0, (size_t)(NR + N) * 4, stream);
  hist_both_kernel<<<(E + 255) / 256, 256, 0, stream>>>(ver_rows, deg1, deg2, E, N);
  scan1_both<<<NT1 + NT2, 256, 0, stream>>>(deg1, bsum1, NR, NT1, deg2, bsum2, N);
  scan2_both<<<2, 512, 0, stream>>>(bsum1, ptr1, NT1, NR, bsum2, ptr2, NT2, N);
  scan3_both<<<NT1 + NT2, 256, 0, stream>>>(deg1, bsum1, ptr1, NR, NT1,
                                            deg2, bsum2, ptr2, N);
  fill_both_kernel<<<(E + 255) / 256, 256, 0, stream>>>(
      ver_rows, ver_cols, ver_vals, deg1, ptr1, pay1, deg2, ptr2, pay2, E, N);

  // ---- prep: cvt + packed weights (one launch) ----
  const int prep_total = N * 64 + REFF * 8 * 16 * 512 + REFF * 8 * 2 * 512;
  prep_kernel<<<(prep_total + 255) / 256, 256, 0, stream>>>(
      features, Xbf, comps1, bases1, W1p, comps2, bases2, W2p, N);

  // ---- layer 1 ----
  fused_l1<<<(N + 31) / 32, 512, 0, stream>>>(pay1, ptr1, Xbf, W1p, bias1,
                                              out1bf, N);
  // ---- layer 2: transform-first ----
  gemm_l2<<<(N + 63) / 64, 256, 0, stream>>>(out1bf, W2p, Y2, N);
  gather_out_kernel<<<(N + 7) / 8, 256, 0, stream>>>(pay2, ptr2, Y2, bias2,
                                                     (float*)d_out, N);
}